// Round 2
// baseline (1311.318 us; speedup 1.0000x reference)
//
#include <hip/hip_runtime.h>
#include <math.h>

// PEER layer. Selection path (sim) is computed with fp64 accumulation so our
// sim equals the correctly-rounded true value; remaining deviation vs the np
// reference is np's own fp32 GEMM rounding (~2e-7), minimizing top-k flips.
// sim is rounded to fp32 before top-k so score adds / tie semantics are
// bitwise-identical to the reference given the same sim values.
//
//  K1 fold_kernel : M[2048,1024] = keys folded into Wq   (fp64 acc, fp32 out)
//  K2 sim_kernel  : sim[1024,2048] = x @ M^T             (fp64 acc, fp32 out)
//  K3 topk_kernel : per (n,h) top16x/top16y -> staircase top16 of 256 -> softmax
//  K4 gather_kernel: g = softmax_w * gelu(x . down[row]); out = sum g * up[row]
//                   (1.07 GB HBM traffic -> the roofline floor, ~170us)

#define BK 16

__device__ __forceinline__ void mac16(double (&acc)[4][4], float4 av, float4 bv) {
  const double ax = av.x, ay = av.y, az = av.z, aw = av.w;
  const double bx = bv.x, by = bv.y, bz = bv.z, bw = bv.w;
  acc[0][0] += ax * bx; acc[0][1] += ax * by; acc[0][2] += ax * bz; acc[0][3] += ax * bw;
  acc[1][0] += ay * bx; acc[1][1] += ay * by; acc[1][2] += ay * bz; acc[1][3] += ay * bw;
  acc[2][0] += az * bx; acc[2][1] += az * by; acc[2][2] += az * bz; acc[2][3] += az * bw;
  acc[3][0] += aw * bx; acc[3][1] += aw * by; acc[3][2] += aw * bz; acc[3][3] += aw * bw;
}

// ---------------- K1: M_slab(128x1024) = A_slab(128x512) @ B_slab(512x1024)
// slab s in [0,16): p = s>>3, h = s&7
// A[k][c] = keys[h,k,p,c]  (row stride 1024 floats)
// B[c][d] = Wq[p*4096 + h*512 + c][d]
__global__ __launch_bounds__(256) void fold_kernel(
    const float* __restrict__ keys, const float* __restrict__ Wq,
    float* __restrict__ M) {
  __shared__ float As[BK][68];   // transposed: As[c][krow], pad 68 vs 64
  __shared__ float Bs[BK][68];   // direct:     Bs[c][d]
  const int s = blockIdx.z, p = s >> 3, h = s & 7;
  const float* A = keys + h * 131072 + p * 512;          // +k*1024 +c
  const float* B = Wq + (p * 4096 + h * 512) * 1024;     // +c*1024 +d
  float* C = M + (p * 1024 + h * 128) * 1024;            // +k*1024 +d
  const int row0 = blockIdx.y * 64;
  const int d0 = blockIdx.x * 64;
  const int t = threadIdx.x;
  const int tx = t & 15, ty = t >> 4;
  const int arow = t >> 2, ac4 = (t & 3) * 4;
  const int brow = t >> 4, bd4 = (t & 15) * 4;
  double acc[4][4] = {};
  for (int k0 = 0; k0 < 512; k0 += BK) {
    float4 a4 = *(const float4*)(A + (row0 + arow) * 1024 + k0 + ac4);
    float4 b4 = *(const float4*)(B + (k0 + brow) * 1024 + d0 + bd4);
    As[ac4 + 0][arow] = a4.x; As[ac4 + 1][arow] = a4.y;
    As[ac4 + 2][arow] = a4.z; As[ac4 + 3][arow] = a4.w;
    *(float4*)&Bs[brow][bd4] = b4;
    __syncthreads();
#pragma unroll
    for (int kk = 0; kk < BK; ++kk) {
      float4 av = *(const float4*)&As[kk][ty * 4];
      float4 bv = *(const float4*)&Bs[kk][tx * 4];
      mac16(acc, av, bv);
    }
    __syncthreads();
  }
#pragma unroll
  for (int i = 0; i < 4; ++i) {
    float4 o = {(float)acc[i][0], (float)acc[i][1], (float)acc[i][2], (float)acc[i][3]};
    *(float4*)(C + (row0 + ty * 4 + i) * 1024 + d0 + tx * 4) = o;
  }
}

// ---------------- K2: sim[n][r] = sum_d x[n][d] * M[r][d]   (A @ B^T)
__global__ __launch_bounds__(256) void sim_kernel(
    const float* __restrict__ x, const float* __restrict__ M,
    float* __restrict__ sim) {
  __shared__ float As[BK][68];   // As[k][n-local]
  __shared__ float Bs[BK][68];   // Bs[k][r-local]
  const int n0 = blockIdx.y * 64;
  const int r0 = blockIdx.x * 64;
  const int t = threadIdx.x;
  const int tx = t & 15, ty = t >> 4;
  const int arow = t >> 2, ak4 = (t & 3) * 4;
  double acc[4][4] = {};
  for (int k0 = 0; k0 < 1024; k0 += BK) {
    float4 a4 = *(const float4*)(x + (n0 + arow) * 1024 + k0 + ak4);
    float4 b4 = *(const float4*)(M + (r0 + arow) * 1024 + k0 + ak4);
    As[ak4 + 0][arow] = a4.x; As[ak4 + 1][arow] = a4.y;
    As[ak4 + 2][arow] = a4.z; As[ak4 + 3][arow] = a4.w;
    Bs[ak4 + 0][arow] = b4.x; Bs[ak4 + 1][arow] = b4.y;
    Bs[ak4 + 2][arow] = b4.z; Bs[ak4 + 3][arow] = b4.w;
    __syncthreads();
#pragma unroll
    for (int kk = 0; kk < BK; ++kk) {
      float4 av = *(const float4*)&As[kk][ty * 4];
      float4 bv = *(const float4*)&Bs[kk][tx * 4];
      mac16(acc, av, bv);
    }
    __syncthreads();
  }
#pragma unroll
  for (int i = 0; i < 4; ++i) {
    float4 o = {(float)acc[i][0], (float)acc[i][1], (float)acc[i][2], (float)acc[i][3]};
    *(float4*)(sim + (n0 + ty * 4 + i) * 2048 + r0 + tx * 4) = o;
  }
}

// ---------------- K3: per (n,h) thread: top16(x), top16(y), staircase merge, softmax
__device__ __forceinline__ void insert16(float (&v)[16], int (&id)[16],
                                         float nv, int nid) {
  // stable: strictly-greater only => ties keep earlier index first (jax.lax.top_k)
  if (nv > v[15]) {
    v[15] = nv; id[15] = nid;
#pragma unroll
    for (int j = 15; j > 0; --j) {
      if (v[j] > v[j - 1]) {
        float tv = v[j]; v[j] = v[j - 1]; v[j - 1] = tv;
        int ti = id[j]; id[j] = id[j - 1]; id[j - 1] = ti;
      }
    }
  }
}

__global__ __launch_bounds__(256) void topk_kernel(
    const float* __restrict__ sim, int* __restrict__ rows,
    float* __restrict__ wts) {
  const int tid = blockIdx.x * 256 + threadIdx.x;  // 0..8191 = n*8+h
  const int n = tid >> 3, h = tid & 7;
  const float* sx = sim + n * 2048 + h * 128;       // p=0
  const float* sy = sx + 1024;                      // p=1
  float vx[16], vy[16]; int ix[16], iy[16];
#pragma unroll
  for (int j = 0; j < 16; ++j) { vx[j] = -1e30f; vy[j] = -1e30f; ix[j] = 0; iy[j] = 0; }
  for (int k = 0; k < 128; ++k) {
    insert16(vx, ix, sx[k], k);
    insert16(vy, iy, sy[k], k);
  }
  // cartesian top-16 of 256; only (i+1)*(j+1)<=16 can make the cut (dominance),
  // processed in flat-index order (i asc, j asc) for stable ties.
  constexpr int JMAX[16] = {16, 8, 5, 4, 3, 2, 2, 2, 1, 1, 1, 1, 1, 1, 1, 1};
  float cv[16]; int cid[16];
#pragma unroll
  for (int j = 0; j < 16; ++j) { cv[j] = -1e30f; cid[j] = 0; }
#pragma unroll
  for (int i = 0; i < 16; ++i) {
#pragma unroll
    for (int j = 0; j < 16; ++j) {
      if (j < JMAX[i]) {
        insert16(cv, cid, vx[i] + vy[j], ix[i] * 128 + iy[j]);
      }
    }
  }
  // softmax over the 16 selected scores (cv[0] is the max)
  float e[16], se = 0.f;
#pragma unroll
  for (int j = 0; j < 16; ++j) { e[j] = expf(cv[j] - cv[0]); se += e[j]; }
  const float inv = 1.0f / se;
#pragma unroll
  for (int j = 0; j < 16; ++j) {
    rows[tid * 16 + j] = h * 16384 + cid[j];
    wts[tid * 16 + j] = e[j] * inv;
  }
}

// ---------------- K4: one block per token. Phase A: g[i]=w*gelu(x.down[row_i]);
// Phase B: out[n] = sum_i g[i]*up[row_i]
__global__ __launch_bounds__(256) void gather_kernel(
    const float* __restrict__ x, const float* __restrict__ up,
    const float* __restrict__ down, const int* __restrict__ rows,
    const float* __restrict__ wts, float* __restrict__ out) {
  __shared__ float xs[1024];
  __shared__ float gs[128];
  __shared__ int rS[128];
  __shared__ float wS[128];
  const int n = blockIdx.x;
  const int t = threadIdx.x;
  ((float4*)xs)[t] = ((const float4*)(x + n * 1024))[t];
  if (t < 128) { rS[t] = rows[n * 128 + t]; wS[t] = wts[n * 128 + t]; }
  __syncthreads();
  const int wave = t >> 6, lane = t & 63;
  const float4* xp = (const float4*)xs;
  for (int it = 0; it < 32; ++it) {
    const int i = it * 4 + wave;
    const long row = rS[i];
    const float4* dp = (const float4*)(down + row * 1024);
    float acc = 0.f;
#pragma unroll
    for (int j = 0; j < 4; ++j) {
      float4 d4 = dp[lane + 64 * j];
      float4 x4 = xp[lane + 64 * j];
      acc += d4.x * x4.x + d4.y * x4.y + d4.z * x4.z + d4.w * x4.w;
    }
#pragma unroll
    for (int off = 32; off; off >>= 1) acc += __shfl_down(acc, off);
    if (lane == 0) {
      const float v = acc;
      const float g = 0.5f * v * (1.0f + erff(v * 0.70710678118654752f));
      gs[i] = g * wS[i];
    }
  }
  __syncthreads();
  float4 a = {0.f, 0.f, 0.f, 0.f};
  const float4* upb = (const float4*)up;
#pragma unroll 4
  for (int i = 0; i < 128; ++i) {
    const long row = rS[i];
    const float g = gs[i];
    float4 u = upb[row * 256 + t];
    a.x += g * u.x; a.y += g * u.y; a.z += g * u.z; a.w += g * u.w;
  }
  ((float4*)out)[n * 256 + t] = a;
}

extern "C" void kernel_launch(void* const* d_in, const int* in_sizes, int n_in,
                              void* d_out, int out_size, void* d_ws, size_t ws_size,
                              hipStream_t stream) {
  const float* x = (const float*)d_in[0];
  const float* Wq = (const float*)d_in[1];
  const float* keys = (const float*)d_in[2];
  const float* up = (const float*)d_in[3];
  const float* down = (const float*)d_in[4];
  float* out = (float*)d_out;
  float* ws = (float*)d_ws;
  // workspace layout (floats): M[2048*1024] | sim[1024*2048] | rows[8192*16] | wts[8192*16]
  float* M = ws;
  float* sim = ws + 2097152;
  int* rows = (int*)(ws + 4194304);
  float* wts = ws + 4325376;

  fold_kernel<<<dim3(16, 2, 16), 256, 0, stream>>>(keys, Wq, M);
  sim_kernel<<<dim3(32, 16, 1), 256, 0, stream>>>(x, M, sim);
  topk_kernel<<<32, 256, 0, stream>>>(sim, rows, wts);
  gather_kernel<<<1024, 256, 0, stream>>>(x, up, down, rows, wts, out);
}